// Round 4
// baseline (401.300 us; speedup 1.0000x reference)
//
#include <hip/hip_runtime.h>

// Fused axial attention (RoadTransformer), bf16 LDS / fp32 compute.
// R4: bf16 halves LDS instr count; 8-ch-per-wave P4; 2 blocks/CU (79 KB LDS).

typedef unsigned int u32;

__device__ __forceinline__ float blo(u32 u) { return __uint_as_float(u << 16); }
__device__ __forceinline__ float bhi(u32 u) { return __uint_as_float(u & 0xffff0000u); }
__device__ __forceinline__ unsigned short f2bf(float f) {
  const u32 u = __float_as_uint(f);
  return (unsigned short)((u + 0x7fffu + ((u >> 16) & 1u)) >> 16);   // RNE
}
__device__ __forceinline__ u32 pk2(float a, float b) {
  return (u32)f2bf(a) | ((u32)f2bf(b) << 16);
}
#define UNPK(u4, f) { f[0]=blo((u4).x); f[1]=bhi((u4).x); f[2]=blo((u4).y); f[3]=bhi((u4).y); \
                      f[4]=blo((u4).z); f[5]=bhi((u4).z); f[6]=blo((u4).w); f[7]=bhi((u4).w); }

__global__ __launch_bounds__(512, 4)
void fused_axial(const float* __restrict__ x,
                 const float* __restrict__ w_qkv,
                 const float* __restrict__ rel,
                 const float* __restrict__ bn_qkv,
                 const float* __restrict__ bn_sim,
                 const float* __restrict__ bn_out,
                 float* __restrict__ out) {
  constexpr float EPS = 1e-5f;
  __shared__ __align__(16) unsigned short qkv_t[64][264];  // [h][o] bf16, 33792 B (528B rows: bank-spread)
  __shared__ __align__(16) unsigned short relC[127][40];   // [d][c] bf16, 10160 B (80B rows: bank-spread)
                                                           // c<8: rel[c][d] (qr); 8..15: rel[c][126-d] (kr); 16..31: rel[c][d] (sve)
  __shared__ __align__(16) u32 UB[8192];                   // 32768 B: xs[64][68] u32 | p[4][64][64] bf16 (XOR-swizzled 16B chunks)
  __shared__ float s_qkv[256], t_qkv[256], s_out[256], t_out[256], s_sim[24];

  const int bid = blockIdx.x;
  const int b = (bid & 7) * 128 + (bid >> 3);              // XCD-chunked swizzle (1024 % 8 == 0)
  const int n = b >> 6, w = b & 63;
  const int tid = threadIdx.x, wv = tid >> 6, lane = tid & 63;

  // ---- stage inputs ----
  const float* xb = x + n * 524288 + w;                    // x[n][c][h][w]
  for (int idx = tid; idx < 4096; idx += 512) {
    const int h = idx & 63, cp = idx >> 6;                 // channel pair
    const float a0 = xb[(2 * cp) * 4096 + h * 64];
    const float a1 = xb[(2 * cp + 1) * 4096 + h * 64];
    UB[h * 68 + cp] = pk2(a0, a1);                         // xs[h][c] bf16
  }
  for (int idx = tid; idx < 4064; idx += 512) {            // 127 * 32
    const int d = idx >> 5, c = idx & 31;
    const int rr = (c >= 8 && c < 16) ? (126 - d) : d;
    relC[d][c] = f2bf(rel[c * 127 + rr]);
  }
  if (tid < 256) {
    float ga = bn_qkv[tid], be = bn_qkv[256 + tid], mu = bn_qkv[512 + tid], va = bn_qkv[768 + tid];
    float s = ga * rsqrtf(va + EPS);
    s_qkv[tid] = s; t_qkv[tid] = be - mu * s;
    ga = bn_out[tid]; be = bn_out[256 + tid]; mu = bn_out[512 + tid]; va = bn_out[768 + tid];
    s = ga * rsqrtf(va + EPS);
    s_out[tid] = s; t_out[tid] = be - mu * s;
  } else if (tid < 280) {
    const int c = tid - 256;
    s_sim[c] = bn_sim[c] * rsqrtf(bn_sim[72 + c] + EPS);   // BN shift cancels in softmax
  }
  __syncthreads();

  // ---- P1: qkv_t[h][o] = BN(sum_c w[o][c] xs[h][c]); 32 outputs/wave, lane = h ----
  {
    const int o0 = __builtin_amdgcn_readfirstlane(wv) * 32;
    float acc[32];
    #pragma unroll
    for (int o = 0; o < 32; ++o) acc[o] = 0.f;
    const u32* xr = &UB[lane * 68];
    for (int cp = 0; cp < 64; cp += 4) {                   // 8 input channels / iter
      const uint4 xu = *reinterpret_cast<const uint4*>(xr + cp);
      float xf[8]; UNPK(xu, xf);
      const float* wp = w_qkv + o0 * 128 + cp * 2;         // wave-uniform -> s_load
      #pragma unroll
      for (int o = 0; o < 32; ++o) {
        const float4 wa = *reinterpret_cast<const float4*>(wp + o * 128);
        const float4 wb = *reinterpret_cast<const float4*>(wp + o * 128 + 4);
        acc[o] = fmaf(wa.x, xf[0], acc[o]); acc[o] = fmaf(wa.y, xf[1], acc[o]);
        acc[o] = fmaf(wa.z, xf[2], acc[o]); acc[o] = fmaf(wa.w, xf[3], acc[o]);
        acc[o] = fmaf(wb.x, xf[4], acc[o]); acc[o] = fmaf(wb.y, xf[5], acc[o]);
        acc[o] = fmaf(wb.z, xf[6], acc[o]); acc[o] = fmaf(wb.w, xf[7], acc[o]);
      }
    }
    u32* qrow = reinterpret_cast<u32*>(&qkv_t[lane][o0]);
    #pragma unroll
    for (int k = 0; k < 16; ++k) {
      const int oo = o0 + 2 * k;
      qrow[k] = pk2(s_qkv[oo] * acc[2 * k] + t_qkv[oo],
                    s_qkv[oo + 1] * acc[2 * k + 1] + t_qkv[oo + 1]);
    }
  }
  __syncthreads();

  const int g_l = wv & 3;                                  // group within pass
  const int hh = wv >> 2;                                  // row-half (P3) / channel-half (P4)
  unsigned short* const pbuf = reinterpret_cast<unsigned short*>(UB);

  for (int pass = 0; pass < 2; ++pass) {
    const int g = pass * 4 + g_l;
    const int gc = g * 32;

    // ---- P3: e = exp(logit); lane = j, rows hh*32 .. hh*32+31 ----
    {
      const uint4 ku = *reinterpret_cast<const uint4*>(&qkv_t[lane][gc + 8]);
      float kf[8]; UNPK(ku, kf);
      const float sqk = s_sim[g], sqr = s_sim[8 + g], skr = s_sim[16 + g];
      for (int r = 0; r < 32; ++r) {
        const int i = hh * 32 + r;
        const uint4 qu = *reinterpret_cast<const uint4*>(&qkv_t[i][gc]);     // uniform
        const int d = i - lane + 63;                                         // 0..126
        const uint4 r1 = *reinterpret_cast<const uint4*>(&relC[d][0]);
        const uint4 r2 = *reinterpret_cast<const uint4*>(&relC[d][8]);
        float qf[8], ra[8], rb[8];
        UNPK(qu, qf); UNPK(r1, ra); UNPK(r2, rb);
        float qk = 0.f, qr = 0.f, kr = 0.f;
        #pragma unroll
        for (int c = 0; c < 8; ++c) {
          qk = fmaf(qf[c], kf[c], qk);
          qr = fmaf(qf[c], ra[c], qr);
          kr = fmaf(kf[c], rb[c], kr);
        }
        const float logit = fmaf(sqk, qk, fmaf(sqr, qr, skr * kr));
        // swizzled: ushort off = row*64 + (j ^ ((i&7)<<3))
        pbuf[(g_l * 64 + i) * 64 + (lane ^ ((i & 7) << 3))] = f2bf(__expf(logit));
      }
    }
    __syncthreads();

    // ---- P4: sv/sve + denom; lane = i, 8 channels ch0..ch0+7 of group g ----
    {
      const int ch0 = hh * 8;
      float sv[8], se[8];
      #pragma unroll
      for (int k = 0; k < 8; ++k) { sv[k] = 0.f; se[k] = 0.f; }
      float psum = 0.f;
      const unsigned short* prow = pbuf + (g_l * 64 + lane) * 64;
      const int swz = (lane & 7) << 3;
      for (int j0 = 0; j0 < 64; j0 += 8) {
        const uint4 pu = *reinterpret_cast<const uint4*>(prow + (j0 ^ swz));
        float pf[8]; UNPK(pu, pf);
        psum += ((pf[0] + pf[1]) + (pf[2] + pf[3])) + ((pf[4] + pf[5]) + (pf[6] + pf[7]));
        #pragma unroll
        for (int jj = 0; jj < 8; ++jj) {
          const int j = j0 + jj;
          const uint4 vu = *reinterpret_cast<const uint4*>(&qkv_t[j][gc + 16 + ch0]); // uniform
          const uint4 ru = *reinterpret_cast<const uint4*>(&relC[lane - j + 63][16 + ch0]);
          float vf[8], rf[8];
          UNPK(vu, vf); UNPK(ru, rf);
          const float pv = pf[jj];
          #pragma unroll
          for (int k = 0; k < 8; ++k) {
            sv[k] = fmaf(pv, vf[k], sv[k]);
            se[k] = fmaf(pv, rf[k], se[k]);
          }
        }
      }
      const float inv = 1.0f / psum;
      #pragma unroll
      for (int k = 0; k < 8; ++k) {
        const int p = g * 16 + ch0 + k;
        out[(n * 128 + p) * 4096 + lane * 64 + w] =
            fmaf(s_out[2 * p], inv * sv[k], t_out[2 * p])
          + fmaf(s_out[2 * p + 1], inv * se[k], t_out[2 * p + 1]);
      }
    }
    __syncthreads();
  }
}

extern "C" void kernel_launch(void* const* d_in, const int* in_sizes, int n_in,
                              void* d_out, int out_size, void* d_ws, size_t ws_size,
                              hipStream_t stream) {
  const float* x      = (const float*)d_in[0];
  const float* w_qkv  = (const float*)d_in[1];
  const float* rel    = (const float*)d_in[2];
  const float* bn_qkv = (const float*)d_in[3];
  const float* bn_sim = (const float*)d_in[4];
  const float* bn_out = (const float*)d_in[5];
  float* out = (float*)d_out;
  fused_axial<<<1024, 512, 0, stream>>>(x, w_qkv, rel, bn_qkv, bn_sim, bn_out, out);
}

// Round 5
// 395.815 us; speedup vs baseline: 1.0139x; 1.0139x over previous
//
#include <hip/hip_runtime.h>

// Fused axial attention (RoadTransformer), bf16 LDS / fp32 compute.
// R5: stores go to d_ws in block-contiguous layout (fully coalesced),
//     separate transpose kernel produces out[n][p][h][w]; keeps 2 blocks/CU.

typedef unsigned int u32;

__device__ __forceinline__ float blo(u32 u) { return __uint_as_float(u << 16); }
__device__ __forceinline__ float bhi(u32 u) { return __uint_as_float(u & 0xffff0000u); }
__device__ __forceinline__ unsigned short f2bf(float f) {
  const u32 u = __float_as_uint(f);
  return (unsigned short)((u + 0x7fffu + ((u >> 16) & 1u)) >> 16);   // RNE
}
__device__ __forceinline__ u32 pk2(float a, float b) {
  return (u32)f2bf(a) | ((u32)f2bf(b) << 16);
}
#define UNPK(u4, f) { f[0]=blo((u4).x); f[1]=bhi((u4).x); f[2]=blo((u4).y); f[3]=bhi((u4).y); \
                      f[4]=blo((u4).z); f[5]=bhi((u4).z); f[6]=blo((u4).w); f[7]=bhi((u4).w); }

template<int STAGE>
__global__ __launch_bounds__(512, 4)
void fused_axial(const float* __restrict__ x,
                 const float* __restrict__ w_qkv,
                 const float* __restrict__ rel,
                 const float* __restrict__ bn_qkv,
                 const float* __restrict__ bn_sim,
                 const float* __restrict__ bn_out,
                 float* __restrict__ wsf,
                 float* __restrict__ out) {
  constexpr float EPS = 1e-5f;
  __shared__ __align__(16) unsigned short qkv_t[64][264];  // [h][o] bf16 (528B rows: bank-spread)
  __shared__ __align__(16) unsigned short relC[127][40];   // [d][c] bf16 (80B rows)
                                                           // c<8: rel[c][d] (qr); 8..15: rel[c][126-d] (kr); 16..31: rel[c][d] (sve)
  __shared__ __align__(16) u32 UB[8192];                   // xs[64][68] u32 | p[4][64][64] bf16 (XOR-swizzled)
  __shared__ float s_qkv[256], t_qkv[256], s_out[256], t_out[256], s_sim[24];

  const int bid = blockIdx.x;
  const int b = (bid & 7) * 128 + (bid >> 3);              // XCD-chunked swizzle (1024 % 8 == 0)
  const int n = b >> 6, w = b & 63;
  const int tid = threadIdx.x, wv = tid >> 6, lane = tid & 63;

  // ---- stage inputs ----
  const float* xb = x + n * 524288 + w;                    // x[n][c][h][w]
  for (int idx = tid; idx < 4096; idx += 512) {
    const int h = idx & 63, cp = idx >> 6;                 // channel pair
    const float a0 = xb[(2 * cp) * 4096 + h * 64];
    const float a1 = xb[(2 * cp + 1) * 4096 + h * 64];
    UB[h * 68 + cp] = pk2(a0, a1);                         // xs[h][c] bf16
  }
  for (int idx = tid; idx < 4064; idx += 512) {            // 127 * 32
    const int d = idx >> 5, c = idx & 31;
    const int rr = (c >= 8 && c < 16) ? (126 - d) : d;
    relC[d][c] = f2bf(rel[c * 127 + rr]);
  }
  if (tid < 256) {
    float ga = bn_qkv[tid], be = bn_qkv[256 + tid], mu = bn_qkv[512 + tid], va = bn_qkv[768 + tid];
    float s = ga * rsqrtf(va + EPS);
    s_qkv[tid] = s; t_qkv[tid] = be - mu * s;
    ga = bn_out[tid]; be = bn_out[256 + tid]; mu = bn_out[512 + tid]; va = bn_out[768 + tid];
    s = ga * rsqrtf(va + EPS);
    s_out[tid] = s; t_out[tid] = be - mu * s;
  } else if (tid < 280) {
    const int c = tid - 256;
    s_sim[c] = bn_sim[c] * rsqrtf(bn_sim[72 + c] + EPS);   // BN shift cancels in softmax
  }
  __syncthreads();

  // ---- P1: qkv_t[h][o] = BN(sum_c w[o][c] xs[h][c]); 32 outputs/wave, lane = h ----
  {
    const int o0 = __builtin_amdgcn_readfirstlane(wv) * 32;
    float acc[32];
    #pragma unroll
    for (int o = 0; o < 32; ++o) acc[o] = 0.f;
    const u32* xr = &UB[lane * 68];
    for (int cp = 0; cp < 64; cp += 4) {                   // 8 input channels / iter
      const uint4 xu = *reinterpret_cast<const uint4*>(xr + cp);
      float xf[8]; UNPK(xu, xf);
      const float* wp = w_qkv + o0 * 128 + cp * 2;         // wave-uniform -> s_load
      #pragma unroll
      for (int o = 0; o < 32; ++o) {
        const float4 wa = *reinterpret_cast<const float4*>(wp + o * 128);
        const float4 wb = *reinterpret_cast<const float4*>(wp + o * 128 + 4);
        acc[o] = fmaf(wa.x, xf[0], acc[o]); acc[o] = fmaf(wa.y, xf[1], acc[o]);
        acc[o] = fmaf(wa.z, xf[2], acc[o]); acc[o] = fmaf(wa.w, xf[3], acc[o]);
        acc[o] = fmaf(wb.x, xf[4], acc[o]); acc[o] = fmaf(wb.y, xf[5], acc[o]);
        acc[o] = fmaf(wb.z, xf[6], acc[o]); acc[o] = fmaf(wb.w, xf[7], acc[o]);
      }
    }
    u32* qrow = reinterpret_cast<u32*>(&qkv_t[lane][o0]);
    #pragma unroll
    for (int k = 0; k < 16; ++k) {
      const int oo = o0 + 2 * k;
      qrow[k] = pk2(s_qkv[oo] * acc[2 * k] + t_qkv[oo],
                    s_qkv[oo + 1] * acc[2 * k + 1] + t_qkv[oo + 1]);
    }
  }
  __syncthreads();

  const int g_l = wv & 3;                                  // group within pass
  const int hh = wv >> 2;                                  // row-half (P3) / channel-half (P4)
  unsigned short* const pbuf = reinterpret_cast<unsigned short*>(UB);

  for (int pass = 0; pass < 2; ++pass) {
    const int g = pass * 4 + g_l;
    const int gc = g * 32;

    // ---- P3: e = exp(logit); lane = j, rows hh*32 .. hh*32+31 ----
    {
      const uint4 ku = *reinterpret_cast<const uint4*>(&qkv_t[lane][gc + 8]);
      float kf[8]; UNPK(ku, kf);
      const float sqk = s_sim[g], sqr = s_sim[8 + g], skr = s_sim[16 + g];
      for (int r = 0; r < 32; ++r) {
        const int i = hh * 32 + r;
        const uint4 qu = *reinterpret_cast<const uint4*>(&qkv_t[i][gc]);     // uniform
        const int d = i - lane + 63;                                         // 0..126
        const uint4 r1 = *reinterpret_cast<const uint4*>(&relC[d][0]);
        const uint4 r2 = *reinterpret_cast<const uint4*>(&relC[d][8]);
        float qf[8], ra[8], rb[8];
        UNPK(qu, qf); UNPK(r1, ra); UNPK(r2, rb);
        float qk = 0.f, qr = 0.f, kr = 0.f;
        #pragma unroll
        for (int c = 0; c < 8; ++c) {
          qk = fmaf(qf[c], kf[c], qk);
          qr = fmaf(qf[c], ra[c], qr);
          kr = fmaf(kf[c], rb[c], kr);
        }
        const float logit = fmaf(sqk, qk, fmaf(sqr, qr, skr * kr));
        pbuf[(g_l * 64 + i) * 64 + (lane ^ ((i & 7) << 3))] = f2bf(__expf(logit));
      }
    }
    __syncthreads();

    // ---- P4: sv/sve + denom; lane = i, 8 channels ch0..ch0+7 of group g ----
    {
      const int ch0 = hh * 8;
      float sv[8], se[8];
      #pragma unroll
      for (int k = 0; k < 8; ++k) { sv[k] = 0.f; se[k] = 0.f; }
      float psum = 0.f;
      const unsigned short* prow = pbuf + (g_l * 64 + lane) * 64;
      const int swz = (lane & 7) << 3;
      for (int j0 = 0; j0 < 64; j0 += 8) {
        const uint4 pu = *reinterpret_cast<const uint4*>(prow + (j0 ^ swz));
        float pf[8]; UNPK(pu, pf);
        psum += ((pf[0] + pf[1]) + (pf[2] + pf[3])) + ((pf[4] + pf[5]) + (pf[6] + pf[7]));
        #pragma unroll
        for (int jj = 0; jj < 8; ++jj) {
          const int j = j0 + jj;
          const uint4 vu = *reinterpret_cast<const uint4*>(&qkv_t[j][gc + 16 + ch0]); // uniform
          const uint4 ru = *reinterpret_cast<const uint4*>(&relC[lane - j + 63][16 + ch0]);
          float vf[8], rf[8];
          UNPK(vu, vf); UNPK(ru, rf);
          const float pv = pf[jj];
          #pragma unroll
          for (int k = 0; k < 8; ++k) {
            sv[k] = fmaf(pv, vf[k], sv[k]);
            se[k] = fmaf(pv, rf[k], se[k]);
          }
        }
      }
      const float inv = 1.0f / psum;
      #pragma unroll
      for (int k = 0; k < 8; ++k) {
        const int p = g * 16 + ch0 + k;
        const float val = fmaf(s_out[2 * p], inv * sv[k], t_out[2 * p])
                        + fmaf(s_out[2 * p + 1], inv * se[k], t_out[2 * p + 1]);
        if (STAGE) {
          wsf[b * 8192 + p * 64 + lane] = val;             // coalesced 256B per store
        } else {
          out[(n * 128 + p) * 4096 + lane * 64 + w] = val; // fallback (scatter)
        }
      }
    }
    __syncthreads();
  }
}

// ws[(n*64+w)][p*64+h] -> out[n][p][h][w]; one (n,p) 64x64 tile per block.
// Block->XCD mapping matched to the main kernel's chunk swizzle: tile rows for
// n in {2r, 2r+1} were produced on XCD r, so put this block on XCD r too.
__global__ __launch_bounds__(256, 8)
void transpose_out(const float* __restrict__ wsf, float* __restrict__ out) {
  __shared__ float tile[64][68];
  const int t = blockIdx.x;
  const int r = t & 7, idx = t >> 3;
  const int n = 2 * r + (idx & 1), p = idx >> 1;
  const int tid = threadIdx.x;
  const float* src = wsf + (size_t)(n * 64) * 8192 + p * 64;   // + w*8192 + h
  #pragma unroll
  for (int it = 0; it < 4; ++it) {
    const int ii = it * 256 + tid;
    const int ww = ii >> 4, h0 = (ii & 15) * 4;
    const float4 v = *reinterpret_cast<const float4*>(src + ww * 8192 + h0);
    *reinterpret_cast<float4*>(&tile[ww][h0]) = v;
  }
  __syncthreads();
  float* dst = out + (size_t)(n * 128 + p) * 4096;             // + h*64 + w
  #pragma unroll
  for (int it = 0; it < 4; ++it) {
    const int ii = it * 256 + tid;
    const int h = ii >> 4, w0 = (ii & 15) * 4;
    float4 o;
    o.x = tile[w0 + 0][h]; o.y = tile[w0 + 1][h];
    o.z = tile[w0 + 2][h]; o.w = tile[w0 + 3][h];
    *reinterpret_cast<float4*>(dst + h * 64 + w0) = o;
  }
}

extern "C" void kernel_launch(void* const* d_in, const int* in_sizes, int n_in,
                              void* d_out, int out_size, void* d_ws, size_t ws_size,
                              hipStream_t stream) {
  const float* x      = (const float*)d_in[0];
  const float* w_qkv  = (const float*)d_in[1];
  const float* rel    = (const float*)d_in[2];
  const float* bn_qkv = (const float*)d_in[3];
  const float* bn_sim = (const float*)d_in[4];
  const float* bn_out = (const float*)d_in[5];
  float* out = (float*)d_out;
  float* wsf = (float*)d_ws;
  if (ws_size >= (size_t)1024 * 8192 * 4) {
    fused_axial<1><<<1024, 512, 0, stream>>>(x, w_qkv, rel, bn_qkv, bn_sim, bn_out, wsf, out);
    transpose_out<<<2048, 256, 0, stream>>>(wsf, out);
  } else {
    fused_axial<0><<<1024, 512, 0, stream>>>(x, w_qkv, rel, bn_qkv, bn_sim, bn_out, wsf, out);
  }
}

// Round 6
// 383.693 us; speedup vs baseline: 1.0459x; 1.0316x over previous
//
#include <hip/hip_runtime.h>

// Fused axial attention (RoadTransformer), bf16 LDS / fp32 compute.
// R6: P1 split into 2x acc[16] halves -> fits 64-VGPR budget, NO scratch spill
//     (R4/R5 spilled acc[32]: 947 MB scratch writes). Keeps ws-staging +
//     transpose kernel, 2 blocks/CU, XCD swizzle, bf16 LDS.

typedef unsigned int u32;

__device__ __forceinline__ float blo(u32 u) { return __uint_as_float(u << 16); }
__device__ __forceinline__ float bhi(u32 u) { return __uint_as_float(u & 0xffff0000u); }
__device__ __forceinline__ unsigned short f2bf(float f) {
  const u32 u = __float_as_uint(f);
  return (unsigned short)((u + 0x7fffu + ((u >> 16) & 1u)) >> 16);   // RNE
}
__device__ __forceinline__ u32 pk2(float a, float b) {
  return (u32)f2bf(a) | ((u32)f2bf(b) << 16);
}
#define UNPK(u4, f) { f[0]=blo((u4).x); f[1]=bhi((u4).x); f[2]=blo((u4).y); f[3]=bhi((u4).y); \
                      f[4]=blo((u4).z); f[5]=bhi((u4).z); f[6]=blo((u4).w); f[7]=bhi((u4).w); }

template<int STAGE>
__global__ __launch_bounds__(512, 4)
void fused_axial(const float* __restrict__ x,
                 const float* __restrict__ w_qkv,
                 const float* __restrict__ rel,
                 const float* __restrict__ bn_qkv,
                 const float* __restrict__ bn_sim,
                 const float* __restrict__ bn_out,
                 float* __restrict__ wsf,
                 float* __restrict__ out) {
  constexpr float EPS = 1e-5f;
  __shared__ __align__(16) unsigned short qkv_t[64][264];  // [h][o] bf16 (528B rows: bank-spread)
  __shared__ __align__(16) unsigned short relC[127][40];   // [d][c] bf16 (80B rows)
                                                           // c<8: rel[c][d] (qr); 8..15: rel[c][126-d] (kr); 16..31: rel[c][d] (sve)
  __shared__ __align__(16) u32 UB[8192];                   // xs[64][68] u32 | p[4][64][64] bf16 (XOR-swizzled)
  __shared__ float s_qkv[256], t_qkv[256], s_out[256], t_out[256], s_sim[24];

  const int bid = blockIdx.x;
  const int b = (bid & 7) * 128 + (bid >> 3);              // XCD-chunked swizzle (1024 % 8 == 0)
  const int n = b >> 6, w = b & 63;
  const int tid = threadIdx.x, wv = tid >> 6, lane = tid & 63;

  // ---- stage inputs ----
  const float* xb = x + n * 524288 + w;                    // x[n][c][h][w]
  for (int idx = tid; idx < 4096; idx += 512) {
    const int h = idx & 63, cp = idx >> 6;                 // channel pair
    const float a0 = xb[(2 * cp) * 4096 + h * 64];
    const float a1 = xb[(2 * cp + 1) * 4096 + h * 64];
    UB[h * 68 + cp] = pk2(a0, a1);                         // xs[h][c] bf16
  }
  for (int idx = tid; idx < 4064; idx += 512) {            // 127 * 32
    const int d = idx >> 5, c = idx & 31;
    const int rr = (c >= 8 && c < 16) ? (126 - d) : d;
    relC[d][c] = f2bf(rel[c * 127 + rr]);
  }
  if (tid < 256) {
    float ga = bn_qkv[tid], be = bn_qkv[256 + tid], mu = bn_qkv[512 + tid], va = bn_qkv[768 + tid];
    float s = ga * rsqrtf(va + EPS);
    s_qkv[tid] = s; t_qkv[tid] = be - mu * s;
    ga = bn_out[tid]; be = bn_out[256 + tid]; mu = bn_out[512 + tid]; va = bn_out[768 + tid];
    s = ga * rsqrtf(va + EPS);
    s_out[tid] = s; t_out[tid] = be - mu * s;
  } else if (tid < 280) {
    const int c = tid - 256;
    s_sim[c] = bn_sim[c] * rsqrtf(bn_sim[72 + c] + EPS);   // BN shift cancels in softmax
  }
  __syncthreads();

  // ---- P1: qkv_t[h][o] = BN(sum_c w[o][c] xs[h][c]); 2 halves x 16 outputs/wave ----
  {
    const int ob = __builtin_amdgcn_readfirstlane(wv) * 32;
    const u32* xr = &UB[lane * 68];
    #pragma unroll 1
    for (int half = 0; half < 2; ++half) {
      const int o0 = ob + half * 16;
      float acc[16];
      #pragma unroll
      for (int o = 0; o < 16; ++o) acc[o] = 0.f;
      for (int cp = 0; cp < 64; cp += 4) {                 // 8 input channels / iter
        const uint4 xu = *reinterpret_cast<const uint4*>(xr + cp);
        float xf[8]; UNPK(xu, xf);
        const float* wp = w_qkv + o0 * 128 + cp * 2;       // wave-uniform -> s_load
        #pragma unroll
        for (int o = 0; o < 16; ++o) {
          const float4 wa = *reinterpret_cast<const float4*>(wp + o * 128);
          const float4 wb = *reinterpret_cast<const float4*>(wp + o * 128 + 4);
          acc[o] = fmaf(wa.x, xf[0], acc[o]); acc[o] = fmaf(wa.y, xf[1], acc[o]);
          acc[o] = fmaf(wa.z, xf[2], acc[o]); acc[o] = fmaf(wa.w, xf[3], acc[o]);
          acc[o] = fmaf(wb.x, xf[4], acc[o]); acc[o] = fmaf(wb.y, xf[5], acc[o]);
          acc[o] = fmaf(wb.z, xf[6], acc[o]); acc[o] = fmaf(wb.w, xf[7], acc[o]);
        }
      }
      u32* qrow = reinterpret_cast<u32*>(&qkv_t[lane][o0]);
      #pragma unroll
      for (int k = 0; k < 8; ++k) {
        const int oo = o0 + 2 * k;
        qrow[k] = pk2(s_qkv[oo] * acc[2 * k] + t_qkv[oo],
                      s_qkv[oo + 1] * acc[2 * k + 1] + t_qkv[oo + 1]);
      }
    }
  }
  __syncthreads();

  const int g_l = wv & 3;                                  // group within pass
  const int hh = wv >> 2;                                  // row-half (P3) / channel-half (P4)
  unsigned short* const pbuf = reinterpret_cast<unsigned short*>(UB);

  for (int pass = 0; pass < 2; ++pass) {
    const int g = pass * 4 + g_l;
    const int gc = g * 32;

    // ---- P3: e = exp(logit); lane = j, rows hh*32 .. hh*32+31 ----
    {
      const uint4 ku = *reinterpret_cast<const uint4*>(&qkv_t[lane][gc + 8]);
      float kf[8]; UNPK(ku, kf);
      const float sqk = s_sim[g], sqr = s_sim[8 + g], skr = s_sim[16 + g];
      for (int r = 0; r < 32; ++r) {
        const int i = hh * 32 + r;
        const uint4 qu = *reinterpret_cast<const uint4*>(&qkv_t[i][gc]);     // uniform
        const int d = i - lane + 63;                                         // 0..126
        const uint4 r1 = *reinterpret_cast<const uint4*>(&relC[d][0]);
        const uint4 r2 = *reinterpret_cast<const uint4*>(&relC[d][8]);
        float qf[8], ra[8], rb[8];
        UNPK(qu, qf); UNPK(r1, ra); UNPK(r2, rb);
        float qk = 0.f, qr = 0.f, kr = 0.f;
        #pragma unroll
        for (int c = 0; c < 8; ++c) {
          qk = fmaf(qf[c], kf[c], qk);
          qr = fmaf(qf[c], ra[c], qr);
          kr = fmaf(kf[c], rb[c], kr);
        }
        const float logit = fmaf(sqk, qk, fmaf(sqr, qr, skr * kr));
        pbuf[(g_l * 64 + i) * 64 + (lane ^ ((i & 7) << 3))] = f2bf(__expf(logit));
      }
    }
    __syncthreads();

    // ---- P4: sv/sve + denom; lane = i, 8 channels ch0..ch0+7 of group g ----
    {
      const int ch0 = hh * 8;
      float sv[8], se[8];
      #pragma unroll
      for (int k = 0; k < 8; ++k) { sv[k] = 0.f; se[k] = 0.f; }
      float psum = 0.f;
      const unsigned short* prow = pbuf + (g_l * 64 + lane) * 64;
      const int swz = (lane & 7) << 3;
      for (int j0 = 0; j0 < 64; j0 += 8) {
        const uint4 pu = *reinterpret_cast<const uint4*>(prow + (j0 ^ swz));
        float pf[8]; UNPK(pu, pf);
        psum += ((pf[0] + pf[1]) + (pf[2] + pf[3])) + ((pf[4] + pf[5]) + (pf[6] + pf[7]));
        #pragma unroll
        for (int jj = 0; jj < 8; ++jj) {
          const int j = j0 + jj;
          const uint4 vu = *reinterpret_cast<const uint4*>(&qkv_t[j][gc + 16 + ch0]); // uniform
          const uint4 ru = *reinterpret_cast<const uint4*>(&relC[lane - j + 63][16 + ch0]);
          float vf[8], rf[8];
          UNPK(vu, vf); UNPK(ru, rf);
          const float pv = pf[jj];
          #pragma unroll
          for (int k = 0; k < 8; ++k) {
            sv[k] = fmaf(pv, vf[k], sv[k]);
            se[k] = fmaf(pv, rf[k], se[k]);
          }
        }
      }
      const float inv = 1.0f / psum;
      #pragma unroll
      for (int k = 0; k < 8; ++k) {
        const int p = g * 16 + ch0 + k;
        const float val = fmaf(s_out[2 * p], inv * sv[k], t_out[2 * p])
                        + fmaf(s_out[2 * p + 1], inv * se[k], t_out[2 * p + 1]);
        if (STAGE) {
          wsf[b * 8192 + p * 64 + lane] = val;             // coalesced 256B per store
        } else {
          out[(n * 128 + p) * 4096 + lane * 64 + w] = val; // fallback (scatter)
        }
      }
    }
    __syncthreads();
  }
}

// ws[(n*64+w)][p*64+h] -> out[n][p][h][w]; one (n,p) 64x64 tile per block.
// XCD-matched to the producer's chunk swizzle (rows for n in {2r,2r+1} made on XCD r).
__global__ __launch_bounds__(256, 8)
void transpose_out(const float* __restrict__ wsf, float* __restrict__ out) {
  __shared__ float tile[64][68];
  const int t = blockIdx.x;
  const int r = t & 7, idx = t >> 3;
  const int n = 2 * r + (idx & 1), p = idx >> 1;
  const int tid = threadIdx.x;
  const float* src = wsf + (size_t)(n * 64) * 8192 + p * 64;   // + w*8192 + h
  #pragma unroll
  for (int it = 0; it < 4; ++it) {
    const int ii = it * 256 + tid;
    const int ww = ii >> 4, h0 = (ii & 15) * 4;
    const float4 v = *reinterpret_cast<const float4*>(src + ww * 8192 + h0);
    *reinterpret_cast<float4*>(&tile[ww][h0]) = v;
  }
  __syncthreads();
  float* dst = out + (size_t)(n * 128 + p) * 4096;             // + h*64 + w
  #pragma unroll
  for (int it = 0; it < 4; ++it) {
    const int ii = it * 256 + tid;
    const int h = ii >> 4, w0 = (ii & 15) * 4;
    float4 o;
    o.x = tile[w0 + 0][h]; o.y = tile[w0 + 1][h];
    o.z = tile[w0 + 2][h]; o.w = tile[w0 + 3][h];
    *reinterpret_cast<float4*>(dst + h * 64 + w0) = o;
  }
}

extern "C" void kernel_launch(void* const* d_in, const int* in_sizes, int n_in,
                              void* d_out, int out_size, void* d_ws, size_t ws_size,
                              hipStream_t stream) {
  const float* x      = (const float*)d_in[0];
  const float* w_qkv  = (const float*)d_in[1];
  const float* rel    = (const float*)d_in[2];
  const float* bn_qkv = (const float*)d_in[3];
  const float* bn_sim = (const float*)d_in[4];
  const float* bn_out = (const float*)d_in[5];
  float* out = (float*)d_out;
  float* wsf = (float*)d_ws;
  if (ws_size >= (size_t)1024 * 8192 * 4) {
    fused_axial<1><<<1024, 512, 0, stream>>>(x, w_qkv, rel, bn_qkv, bn_sim, bn_out, wsf, out);
    transpose_out<<<2048, 256, 0, stream>>>(wsf, out);
  } else {
    fused_axial<0><<<1024, 512, 0, stream>>>(x, w_qkv, rel, bn_qkv, bn_sim, bn_out, wsf, out);
  }
}